// Round 1
// baseline (1758.115 us; speedup 1.0000x reference)
//
#include <hip/hip_runtime.h>
#include <stdint.h>

// TopK activation: relu(x), keep top-k per row of 32768, zero the rest.
// One 1024-thread block per row; data lives in registers (32 elems/thread).
// Exact 3-round radix select on positive-float bit patterns gives the k-th
// largest value's exact bits + tie count; ties broken by lowest index
// (matches jax.lax.top_k).

#define NT   1024
#define NCOL 32768
#define VPT  8          // uint4 (4 elems) per thread -> 32 elems/thread
#define NB   2048       // histogram bins per round
#define REP  2          // histogram replicas (atomic contention relief)
#define LISTCAP 2048    // tie-index list capacity (rare path)

__global__ __launch_bounds__(NT) void topk_select_kernel(
        const float* __restrict__ x, const int* __restrict__ kptr,
        float* __restrict__ out)
{
    __shared__ uint32_t hist[REP][NB];
    __shared__ uint32_t tielist[LISTCAP];
    __shared__ int s_found, s_B, s_kth, s_neq, s_cnt, s_cut;

    const int tid  = threadIdx.x;
    const int lane = tid & 63;
    const int wave = tid >> 6;
    const size_t base = (size_t)blockIdx.x * NCOL;

    int k = *kptr;
    if (k > NCOL) k = NCOL;

    const uint4* xv = (const uint4*)(x + base);
    uint4*       ov = (uint4*)(out + base);

    if (k <= 0) {   // uniform across block: safe early-out, write zeros
        #pragma unroll
        for (int j = 0; j < VPT; ++j)
            ov[j * NT + tid] = make_uint4(0u, 0u, 0u, 0u);
        return;
    }

    // ---- load row, map to order-preserving keys (<=0 -> 0) ----
    uint4 va[VPT];
    #pragma unroll
    for (int j = 0; j < VPT; ++j) va[j] = xv[j * NT + tid];
    #pragma unroll
    for (int j = 0; j < VPT; ++j) {
        uint32_t* p = (uint32_t*)&va[j];
        #pragma unroll
        for (int c = 0; c < 4; ++c) {
            uint32_t u = p[c];
            p[c] = ((int)u > 0) ? u : 0u;   // positive float bits are monotonic
        }
    }

    // ---- 3-round radix select for the k-th largest key ----
    int kth = k;            // rank remaining within current candidate set
    uint32_t prefix = 0u;   // selected high bits so far
    uint32_t thr = 0u;      // final exact bits of k-th largest
    int n_eq = 0;           // count of elements equal to thr
    bool done = false;

    #pragma unroll
    for (int round = 0; round < 3; ++round) {
        for (int i = tid; i < REP * NB; i += NT)
            ((uint32_t*)hist)[i] = 0u;
        __syncthreads();

        if (!done) {
            const int r = wave & (REP - 1);
            #pragma unroll
            for (int j = 0; j < VPT; ++j) {
                const uint32_t* p = (const uint32_t*)&va[j];
                #pragma unroll
                for (int c = 0; c < 4; ++c) {
                    uint32_t vv = p[c];
                    bool act; uint32_t bin;
                    if (round == 0)      { act = (vv != 0u);                          bin = vv >> 21; }
                    else if (round == 1) { act = (vv != 0u) && ((vv >> 21) == prefix); bin = (vv >> 10) & 0x7FFu; }
                    else                 { act = (vv != 0u) && ((vv >> 10) == prefix); bin = vv & 0x3FFu; }
                    if (act) atomicAdd(&hist[r][bin], 1u);
                }
            }
        }
        __syncthreads();

        if (wave == 0) {
            // each lane sums a 32-bin group (swizzled to avoid stride-32 bank conflict)
            uint32_t s = 0;
            for (int i = 0; i < 32; ++i) {
                int b = lane * 32 + ((i + lane) & 31);
                #pragma unroll
                for (int r2 = 0; r2 < REP; ++r2) s += hist[r2][b];
            }
            // inclusive suffix sum over 64 group totals
            uint32_t suf = s;
            #pragma unroll
            for (int d = 1; d < 64; d <<= 1) {
                uint32_t t2 = __shfl_down(suf, d);
                if (lane + d < 64) suf += t2;
            }
            uint32_t t1  = __shfl_down(suf, 1);
            uint32_t nxt = (lane == 63) ? 0u : t1;
            bool cond = (!done) && (suf >= (uint32_t)kth) && (nxt < (uint32_t)kth);
            unsigned long long mask = __ballot(cond);
            if (mask == 0ull) {
                if (lane == 0) s_found = 0;   // fewer than kth positive values
            } else {
                int G = __ffsll(mask) - 1;
                uint32_t cntG = __shfl(nxt, G);   // count in groups above G
                // refine within group G's 32 bins
                uint32_t h2 = 0;
                if (lane < 32) {
                    int b = G * 32 + lane;
                    #pragma unroll
                    for (int r2 = 0; r2 < REP; ++r2) h2 += hist[r2][b];
                }
                uint32_t suf2 = h2;
                #pragma unroll
                for (int d = 1; d < 64; d <<= 1) {
                    uint32_t t2 = __shfl_down(suf2, d);
                    if (lane + d < 64) suf2 += t2;
                }
                uint32_t t3   = __shfl_down(suf2, 1);
                uint32_t nxt2 = (lane == 63) ? 0u : t3;
                uint32_t ts   = cntG + suf2;
                uint32_t tsn  = cntG + nxt2;
                bool cond2 = (lane < 32) && (ts >= (uint32_t)kth) && (tsn < (uint32_t)kth);
                unsigned long long m2 = __ballot(cond2);
                int l = __ffsll(m2) - 1;
                uint32_t ngt  = __shfl(tsn, l);          // strictly-greater count
                uint32_t cbin = __shfl(suf2 - nxt2, l);  // count at selected bin
                if (lane == 0) {
                    s_found = 1;
                    s_B   = G * 32 + l;
                    s_kth = kth - (int)ngt;
                    s_neq = (int)cbin;
                }
            }
        }
        __syncthreads();

        if (!done) {
            if (!s_found) { done = true; thr = 0u; }
            else {
                int B = s_B;
                kth  = s_kth;
                n_eq = s_neq;
                if (round == 0)      prefix = (uint32_t)B;
                else if (round == 1) prefix = (prefix << 11) | (uint32_t)B;
                else                 thr    = (prefix << 10) | (uint32_t)B;
            }
        }
        __syncthreads();
    }
    // Now: elements with key > thr are kept (k - kth of them), plus the
    // kth smallest-index elements among key == thr. n_eq == kth => keep all ties.

    if (tid == 0) s_cnt = 0;
    __syncthreads();
    const bool need_tb = (thr != 0u) && (n_eq != kth);   // block-uniform
    if (need_tb) {
        #pragma unroll
        for (int j = 0; j < VPT; ++j) {
            const uint32_t* p = (const uint32_t*)&va[j];
            #pragma unroll
            for (int c = 0; c < 4; ++c) {
                if (p[c] == thr) {
                    int slot = atomicAdd(&s_cnt, 1);
                    if (slot < LISTCAP)
                        tielist[slot] = (uint32_t)(j * 4096 + tid * 4 + c);
                }
            }
        }
    }
    __syncthreads();
    if (need_tb && tid == 0) {
        int n = s_cnt; if (n > LISTCAP) n = LISTCAP;
        for (int i = 1; i < n; ++i) {            // tiny insertion sort (rare path)
            uint32_t key = tielist[i]; int j2 = i - 1;
            while (j2 >= 0 && tielist[j2] > key) { tielist[j2 + 1] = tielist[j2]; --j2; }
            tielist[j2 + 1] = key;
        }
        s_cut = (kth >= 1 && kth <= n) ? (int)tielist[kth - 1] : 0x7FFFFFFF;
    }
    __syncthreads();
    const int idx_cut = need_tb ? s_cut : 0x7FFFFFFF;

    // ---- write output from registers ----
    #pragma unroll
    for (int j = 0; j < VPT; ++j) {
        const uint32_t* p = (const uint32_t*)&va[j];
        uint4 o;
        uint32_t* q = (uint32_t*)&o;
        #pragma unroll
        for (int c = 0; c < 4; ++c) {
            uint32_t vv = p[c];
            int idx = j * 4096 + tid * 4 + c;
            bool keep = (vv > thr) || (thr != 0u && vv == thr && idx <= idx_cut);
            q[c] = keep ? vv : 0u;
        }
        ov[j * NT + tid] = o;
    }
}

extern "C" void kernel_launch(void* const* d_in, const int* in_sizes, int n_in,
                              void* d_out, int out_size, void* d_ws, size_t ws_size,
                              hipStream_t stream) {
    const float* x    = (const float*)d_in[0];
    const int*   kptr = (const int*)d_in[1];
    float*       out  = (float*)d_out;
    const int rows = in_sizes[0] / NCOL;
    topk_select_kernel<<<rows, NT, 0, stream>>>(x, kptr, out);
}